// Round 4
// baseline (823.925 us; speedup 1.0000x reference)
//
#include <hip/hip_runtime.h>
#include <math.h>

#define BATCH 2048
#define FID 65536
#define NT 256
#define NV (FID / 4)                  // 16384 vf4 per row
#define GRID 2048
#define CHUNK 1024                    // vf4 per chunk = 16 KiB
#define CPR (NV / CHUNK)              // 16 chunks per row
#define NIT (BATCH * NV / (GRID * CHUNK))   // 16 front steps
#define SLOTS 64                      // per-row partials: 16 blocks x 4 waves

typedef float vf4 __attribute__((ext_vector_type(4)));

// R13: MEASUREMENT ROUND. Four structurally disjoint kernels (R9-R12) all
// land 655-693 us; the bottleneck identity is unknown because lr_sweep never
// appears in rocprof top-5 (cutoff ~330 us). Two worlds fit the data:
//   (a) kernel ~320 us (reads capped ~1.7 TB/s, ~230 us headroom)
//   (b) kernel ~90-120 us (already at BW roofline; window is harness floor)
// lr_sweep is idempotent (plain stores of pure functions of inputs), so we
// launch it 3x: T_kernel = (dur - 664.6)/2 exactly. Predictions:
//   world (a): dur ~1300, lr_sweep may show in top-5 @ ~1.7 TB/s
//   world (b): dur ~845, top-5 all fills
// Kernel body is byte-identical to R11 (nt variant, best structure).
__global__ __launch_bounds__(NT, 8) void lr_sweep(
        const float* __restrict__ gate,
        const float* __restrict__ bias,
        float* __restrict__ ws) {     // [BATCH][SLOTS] partials
    const int bid  = blockIdx.x;
    const int tid  = threadIdx.x;
    const int wave = tid >> 6;
    const int lane = tid & 63;
    const vf4* __restrict__ b4 = (const vf4*)bias;
    const vf4* __restrict__ g4 = (const vf4*)gate;

    // bias fragment for this block's (constant) within-row chunk: 4 vf4/thread
    const int bb = (bid & (CPR - 1)) * CHUNK + tid;
    const vf4 v0 = b4[bb];
    const vf4 v1 = b4[bb + NT];
    const vf4 v2 = b4[bb + 2 * NT];
    const vf4 v3 = b4[bb + 3 * NT];

    const vf4* __restrict__ gp = g4 + (size_t)bid * CHUNK + tid;
    const int slot = (bid & (CPR - 1)) * 4 + wave;
    const int row0 = bid >> 4;        // bid / CPR

    for (int t = 0; t < NIT; ++t) {
        const vf4* p = gp + (size_t)t * (GRID * CHUNK);
        vf4 g0 = __builtin_nontemporal_load(&p[0]);
        vf4 g1 = __builtin_nontemporal_load(&p[NT]);
        vf4 g2 = __builtin_nontemporal_load(&p[2 * NT]);
        vf4 g3 = __builtin_nontemporal_load(&p[3 * NT]);

        float a = g0.x * v0.x;
        a = fmaf(g0.y, v0.y, a); a = fmaf(g0.z, v0.z, a); a = fmaf(g0.w, v0.w, a);
        a = fmaf(g1.x, v1.x, a); a = fmaf(g1.y, v1.y, a);
        a = fmaf(g1.z, v1.z, a); a = fmaf(g1.w, v1.w, a);
        float b = g2.x * v2.x;
        b = fmaf(g2.y, v2.y, b); b = fmaf(g2.z, v2.z, b); b = fmaf(g2.w, v2.w, b);
        b = fmaf(g3.x, v3.x, b); b = fmaf(g3.y, v3.y, b);
        b = fmaf(g3.z, v3.z, b); b = fmaf(g3.w, v3.w, b);
        a += b;

        #pragma unroll
        for (int off = 32; off > 0; off >>= 1)
            a += __shfl_down(a, off, 64);

        if (lane == 0)
            ws[(size_t)(row0 + t * (GRID / CPR)) * SLOTS + slot] = a;
    }
}

// Finisher: reduce 64 partials/row, add gbias, write logits + pred, loss.
__global__ __launch_bounds__(NT) void lr_finish(
        const float* __restrict__ ws,
        const float* __restrict__ gbias,
        const float* __restrict__ label,
        float* __restrict__ out) {
    const float gb = gbias[0];
    float acc = 0.0f;
    for (int r = threadIdx.x; r < BATCH; r += NT) {
        const vf4* w = (const vf4*)(ws + (size_t)r * SLOTS);
        vf4 s4 = w[0];
        #pragma unroll
        for (int j = 1; j < SLOTS / 4; ++j) {
            vf4 t = w[j];
            s4.x += t.x; s4.y += t.y; s4.z += t.z; s4.w += t.w;
        }
        float x = (s4.x + s4.y) + (s4.z + s4.w) + gb;
        float l = label[r];
        out[r] = x;                                 // final logit
        out[BATCH + r] = 1.0f / (1.0f + expf(-x));  // pred
        acc += fmaxf(x, 0.0f) - x * l + log1pf(expf(-fabsf(x)));
    }
    #pragma unroll
    for (int off = 32; off > 0; off >>= 1)
        acc += __shfl_down(acc, off, 64);

    __shared__ float wsum[NT / 64];
    const int wave = threadIdx.x >> 6;
    const int lane = threadIdx.x & 63;
    if (lane == 0) wsum[wave] = acc;
    __syncthreads();
    if (threadIdx.x == 0)
        out[2 * BATCH] = wsum[0] + wsum[1] + wsum[2] + wsum[3];
}

extern "C" void kernel_launch(void* const* d_in, const int* in_sizes, int n_in,
                              void* d_out, int out_size, void* d_ws, size_t ws_size,
                              hipStream_t stream) {
    const float* gate  = (const float*)d_in[0];  // [BATCH, FID]
    const float* bias  = (const float*)d_in[1];  // [FID]
    const float* gbias = (const float*)d_in[2];  // [1]
    const float* label = (const float*)d_in[3];  // [BATCH]
    float* out = (float*)d_out;                  // [logits | pred | loss]
    float* ws  = (float*)d_ws;                   // [BATCH][SLOTS] partials

    // Launch the (idempotent) sweep 3x: dur slope gives T_kernel exactly.
    lr_sweep<<<GRID, NT, 0, stream>>>(gate, bias, ws);
    lr_sweep<<<GRID, NT, 0, stream>>>(gate, bias, ws);
    lr_sweep<<<GRID, NT, 0, stream>>>(gate, bias, ws);
    lr_finish<<<1, NT, 0, stream>>>(ws, gbias, label, out);
}

// Round 5
// 663.848 us; speedup vs baseline: 1.2411x; 1.2411x over previous
//
#include <hip/hip_runtime.h>
#include <math.h>

#define BATCH 2048
#define FID 65536
#define NT 256
#define NV (FID / 4)                  // 16384 vf4 per row
#define GRID 2048
#define CHUNK 1024                    // vf4 per chunk = 16 KiB
#define CPR (NV / CHUNK)              // 16 chunks per row
#define NIT (BATCH * NV / (GRID * CHUNK))   // 16 front steps
#define SLOTS 64                      // per-row partials: 16 blocks x 4 waves

typedef float vf4 __attribute__((ext_vector_type(4)));

// R14 = R11 body, single launch (reverting R13's 3x slope instrumentation).
// R13's slope measurement settled the bottleneck question:
//   T(lr_sweep) = (823.9 - 664.6)/2 = 79.7 us  =>  536.9 MB / 79.7 us
//   = 6.74 TB/s -- AT the HBM roofline (m13 plain-copy ceiling 6.29 TB/s).
// The ~655 us window is ~575 us of harness dispatches (the ~330 us 2-GiB
// poison fill + sub-top-5 restores) + ~80 us sweep + ~5 us finish.
// R9-R12's shape-invariance is explained: all four structures were already
// roofline-bound. nt on gate is kept: removing it cost +29 us twice (R7,
// R12) -- plain loads allocate L2/L3 on a zero-reuse 512 MiB stream.
// Do NOT fuse finish into sweep: R8's last-block-done + __threadfence
// regressed +384 us (device-scope fence -> per-block L2 writeback on
// non-coherent per-XCD L2s).
__global__ __launch_bounds__(NT, 8) void lr_sweep(
        const float* __restrict__ gate,
        const float* __restrict__ bias,
        float* __restrict__ ws) {     // [BATCH][SLOTS] partials
    const int bid  = blockIdx.x;
    const int tid  = threadIdx.x;
    const int wave = tid >> 6;
    const int lane = tid & 63;
    const vf4* __restrict__ b4 = (const vf4*)bias;
    const vf4* __restrict__ g4 = (const vf4*)gate;

    // bias fragment for this block's (constant) within-row chunk: 4 vf4/thread
    const int bb = (bid & (CPR - 1)) * CHUNK + tid;
    const vf4 v0 = b4[bb];
    const vf4 v1 = b4[bb + NT];
    const vf4 v2 = b4[bb + 2 * NT];
    const vf4 v3 = b4[bb + 3 * NT];

    const vf4* __restrict__ gp = g4 + (size_t)bid * CHUNK + tid;
    const int slot = (bid & (CPR - 1)) * 4 + wave;
    const int row0 = bid >> 4;        // bid / CPR

    for (int t = 0; t < NIT; ++t) {
        const vf4* p = gp + (size_t)t * (GRID * CHUNK);
        vf4 g0 = __builtin_nontemporal_load(&p[0]);
        vf4 g1 = __builtin_nontemporal_load(&p[NT]);
        vf4 g2 = __builtin_nontemporal_load(&p[2 * NT]);
        vf4 g3 = __builtin_nontemporal_load(&p[3 * NT]);

        float a = g0.x * v0.x;
        a = fmaf(g0.y, v0.y, a); a = fmaf(g0.z, v0.z, a); a = fmaf(g0.w, v0.w, a);
        a = fmaf(g1.x, v1.x, a); a = fmaf(g1.y, v1.y, a);
        a = fmaf(g1.z, v1.z, a); a = fmaf(g1.w, v1.w, a);
        float b = g2.x * v2.x;
        b = fmaf(g2.y, v2.y, b); b = fmaf(g2.z, v2.z, b); b = fmaf(g2.w, v2.w, b);
        b = fmaf(g3.x, v3.x, b); b = fmaf(g3.y, v3.y, b);
        b = fmaf(g3.z, v3.z, b); b = fmaf(g3.w, v3.w, b);
        a += b;

        #pragma unroll
        for (int off = 32; off > 0; off >>= 1)
            a += __shfl_down(a, off, 64);

        if (lane == 0)
            ws[(size_t)(row0 + t * (GRID / CPR)) * SLOTS + slot] = a;
    }
}

// Finisher: reduce 64 partials/row, add gbias, write logits + pred, loss.
__global__ __launch_bounds__(NT) void lr_finish(
        const float* __restrict__ ws,
        const float* __restrict__ gbias,
        const float* __restrict__ label,
        float* __restrict__ out) {
    const float gb = gbias[0];
    float acc = 0.0f;
    for (int r = threadIdx.x; r < BATCH; r += NT) {
        const vf4* w = (const vf4*)(ws + (size_t)r * SLOTS);
        vf4 s4 = w[0];
        #pragma unroll
        for (int j = 1; j < SLOTS / 4; ++j) {
            vf4 t = w[j];
            s4.x += t.x; s4.y += t.y; s4.z += t.z; s4.w += t.w;
        }
        float x = (s4.x + s4.y) + (s4.z + s4.w) + gb;
        float l = label[r];
        out[r] = x;                                 // final logit
        out[BATCH + r] = 1.0f / (1.0f + expf(-x));  // pred
        acc += fmaxf(x, 0.0f) - x * l + log1pf(expf(-fabsf(x)));
    }
    #pragma unroll
    for (int off = 32; off > 0; off >>= 1)
        acc += __shfl_down(acc, off, 64);

    __shared__ float wsum[NT / 64];
    const int wave = threadIdx.x >> 6;
    const int lane = threadIdx.x & 63;
    if (lane == 0) wsum[wave] = acc;
    __syncthreads();
    if (threadIdx.x == 0)
        out[2 * BATCH] = wsum[0] + wsum[1] + wsum[2] + wsum[3];
}

extern "C" void kernel_launch(void* const* d_in, const int* in_sizes, int n_in,
                              void* d_out, int out_size, void* d_ws, size_t ws_size,
                              hipStream_t stream) {
    const float* gate  = (const float*)d_in[0];  // [BATCH, FID]
    const float* bias  = (const float*)d_in[1];  // [FID]
    const float* gbias = (const float*)d_in[2];  // [1]
    const float* label = (const float*)d_in[3];  // [BATCH]
    float* out = (float*)d_out;                  // [logits | pred | loss]
    float* ws  = (float*)d_ws;                   // [BATCH][SLOTS] partials

    // Every ws slot and every out slot is written before read -> no memsets.
    lr_sweep<<<GRID, NT, 0, stream>>>(gate, bias, ws);
    lr_finish<<<1, NT, 0, stream>>>(ws, gbias, label, out);
}